// Round 7
// baseline (422.064 us; speedup 1.0000x reference)
//
#include <hip/hip_runtime.h>

// ---------------------------------------------------------------------------
// GIN encoder, fp16 feature path + MFMA, fused per-layer kernel (512 thr).
// layer_kernel: per 64-row block, 8 waves:
//   phase A: CSR gather. Per row: ONE coalesced load of the 64-edge index
//            window (srcs[base+lane]), then readlane-broadcast each index and
//            issue 8 independent row-gathers at a time (no idx->gather
//            dependency chain; round 6 was latency-bound on that chain).
//            + fused BN of the PREVIOUS layer -> swizzled LDS tile
//   GEMM1: 8-way wave split (wr=wave&3 rows, wc=wave>>2 col-half) -> ReLU
//          -> same LDS tile
//   GEMM2: same split -> bias+ReLU -> Hout + per-block column stats -> pstat
// bn_stats_kernel reduces pstat -> scale/shift. Last layer BN folds into
// pool_proj_kernel.
// ---------------------------------------------------------------------------

typedef __attribute__((ext_vector_type(8))) _Float16 f16x8;
typedef __attribute__((ext_vector_type(4))) float f32x4;

static __device__ __forceinline__ float h2f(unsigned short u) {
  return (float)__builtin_bit_cast(_Float16, u);
}
static __device__ __forceinline__ unsigned short f2h(float f) {
  return __builtin_bit_cast(unsigned short, (_Float16)f);
}
static __device__ __forceinline__ float lo16(unsigned int v) { return h2f((unsigned short)(v & 0xffffu)); }
static __device__ __forceinline__ float hi16(unsigned int v) { return h2f((unsigned short)(v >> 16)); }

// ---- CSR build ----
__global__ __launch_bounds__(256) void hist_kernel(const int* __restrict__ dst,
                                                   int* __restrict__ counts, int E) {
  int e = blockIdx.x * 256 + threadIdx.x;
  if (e < E) atomicAdd(&counts[dst[e]], 1);
}

__global__ __launch_bounds__(512) void scan1_kernel(const int* __restrict__ counts,
                                                    int* __restrict__ incl,
                                                    int* __restrict__ bsums, int n) {
  __shared__ int buf[2][512];
  int t = threadIdx.x;
  int i = blockIdx.x * 512 + t;
  buf[0][t] = (i < n) ? counts[i] : 0;
  __syncthreads();
  int cur = 0;
  for (int off = 1; off < 512; off <<= 1) {
    buf[cur ^ 1][t] = buf[cur][t] + ((t >= off) ? buf[cur][t - off] : 0);
    __syncthreads();
    cur ^= 1;
  }
  if (i < n) incl[i] = buf[cur][t];
  if (t == 511) bsums[blockIdx.x] = buf[cur][511];
}

__global__ __launch_bounds__(128) void scan2_kernel(int* __restrict__ bsums, int nb) {
  __shared__ int buf[2][128];
  int t = threadIdx.x;
  int v = (t < nb) ? bsums[t] : 0;
  buf[0][t] = v;
  __syncthreads();
  int cur = 0;
  for (int off = 1; off < 128; off <<= 1) {
    buf[cur ^ 1][t] = buf[cur][t] + ((t >= off) ? buf[cur][t - off] : 0);
    __syncthreads();
    cur ^= 1;
  }
  if (t < nb) bsums[t] = buf[cur][t] - v;  // exclusive
}

__global__ __launch_bounds__(256) void scan3_kernel(const int* __restrict__ counts,
                                                    const int* __restrict__ incl,
                                                    const int* __restrict__ bsums,
                                                    int* __restrict__ offsets,
                                                    int* __restrict__ cursor, int n) {
  int i = blockIdx.x * 256 + threadIdx.x;
  if (i < n) {
    int total = bsums[i >> 9] + incl[i];
    offsets[i + 1] = total;
    cursor[i] = total - counts[i];
  }
  if (i == 0) offsets[0] = 0;
}

__global__ __launch_bounds__(256) void fill_kernel(const int* __restrict__ src,
                                                   const int* __restrict__ dst,
                                                   int* cursor, int* __restrict__ srcs, int E) {
  int e = blockIdx.x * 256 + threadIdx.x;
  if (e < E) {
    int p = atomicAdd(&cursor[dst[e]], 1);
    __builtin_nontemporal_store(src[e], &srcs[p]);
  }
}

// ---- prep: x -> fp16 row-major (uint-packed); zero counts; init affine ----
__global__ __launch_bounds__(256) void prep_kernel(const float* __restrict__ x,
                                                   unsigned int* __restrict__ h,
                                                   int* __restrict__ counts,
                                                   float* __restrict__ scale,
                                                   float* __restrict__ shift, int M) {
  int stride = gridDim.x * 256;
  int tid = blockIdx.x * 256 + threadIdx.x;
  const float2* x2 = (const float2*)x;
  int total = M * 64;
  for (int i = tid; i < total; i += stride) {
    float2 v = x2[i];
    h[i] = (unsigned int)f2h(v.x) | ((unsigned int)f2h(v.y) << 16);
  }
  for (int i = tid; i < M; i += stride) counts[i] = 0;
  if (tid < 128) { scale[tid] = 1.f; shift[tid] = 0.f; }
}

// WT[m][n][k] = f16(W_m[k][n]), m in [0, 2L): even=W1 layer m/2, odd=W2 layer m/2
__global__ __launch_bounds__(256) void prep_w_kernel(const float* __restrict__ W1,
                                                     const float* __restrict__ W2,
                                                     unsigned short* __restrict__ WT, int total) {
  int idx = blockIdx.x * 256 + threadIdx.x;
  if (idx >= total) return;
  int m = idx >> 14;
  int rem = idx & 16383;
  int n = rem >> 7, k = rem & 127;
  const float* W = ((m & 1) == 0) ? (W1 + (size_t)(m >> 1) * 16384)
                                  : (W2 + (size_t)(m >> 1) * 16384);
  WT[idx] = f2h(W[k * 128 + n]);
}

// ---- fused layer: gather+BN -> LDS -> GEMM1 -> LDS -> GEMM2 -> Hout+stats ----
// LDS tile swizzle: fp16 col c of row rl lives at byte (rl*256 + ((c*2) ^ ((rl&7)<<4))).
// MFMA frag layouts (m89-verified, used in passing rounds 3-6):
//   A/B: lane holds X[(l&15)][ks*32 + (l>>4)*8 + j]; C/D: col=lane&15, row=(lane>>4)*4+reg.
__global__ __launch_bounds__(512, 8) void layer_kernel(
    const unsigned int* __restrict__ Hin,  // M x 64 uints (fp16x2, row-major)
    const int* __restrict__ offsets, const int* __restrict__ srcs,
    const float* __restrict__ scale, const float* __restrict__ shift,
    const unsigned short* __restrict__ WT1, const float* __restrict__ b1,
    const unsigned short* __restrict__ WT2, const float* __restrict__ b2,
    unsigned short* __restrict__ Hout,  // M x 128 fp16 row-major
    float* __restrict__ pstat, int M) {
  __shared__ unsigned short sT[64 * 128];
  __shared__ float s_sum[128], s_sq[128];
  int t = threadIdx.x;
  if (t < 128) { s_sum[t] = 0.f; s_sq[t] = 0.f; }
  int wave = t >> 6, lane = t & 63;
  int row0 = blockIdx.x * 64;
  char* sTb = (char*)sT;
  float sc0 = scale[2 * lane], sc1 = scale[2 * lane + 1];
  float sh0 = shift[2 * lane], sh1 = shift[2 * lane + 1];

  // ---- phase A: gather + prev-layer BN; wave owns 8 rows ----
  for (int i = 0; i < 8; ++i) {
    int r = row0 + wave * 8 + i;
    int rl_ = wave * 8 + i;
    if (r < M) {
      int e0 = offsets[r], e1 = offsets[r + 1];
      unsigned int self = Hin[(size_t)r * 64 + lane];
      float ax = lo16(self), ay = hi16(self);
      for (int base = e0; base < e1; base += 64) {
        int cnt = min(64, e1 - base);
        int idx = 0;
        if (base + lane < e1) idx = srcs[base + lane];  // one coalesced idx load
        int j = 0;
        for (; j + 8 <= cnt; j += 8) {
          // 8 independent gathers in flight (indices via readlane, no mem dep)
          int s0 = __builtin_amdgcn_readlane(idx, j + 0);
          int s1 = __builtin_amdgcn_readlane(idx, j + 1);
          int s2 = __builtin_amdgcn_readlane(idx, j + 2);
          int s3 = __builtin_amdgcn_readlane(idx, j + 3);
          int s4 = __builtin_amdgcn_readlane(idx, j + 4);
          int s5 = __builtin_amdgcn_readlane(idx, j + 5);
          int s6 = __builtin_amdgcn_readlane(idx, j + 6);
          int s7 = __builtin_amdgcn_readlane(idx, j + 7);
          unsigned int v0 = Hin[(size_t)s0 * 64 + lane];
          unsigned int v1 = Hin[(size_t)s1 * 64 + lane];
          unsigned int v2 = Hin[(size_t)s2 * 64 + lane];
          unsigned int v3 = Hin[(size_t)s3 * 64 + lane];
          unsigned int v4 = Hin[(size_t)s4 * 64 + lane];
          unsigned int v5 = Hin[(size_t)s5 * 64 + lane];
          unsigned int v6 = Hin[(size_t)s6 * 64 + lane];
          unsigned int v7 = Hin[(size_t)s7 * 64 + lane];
          ax += lo16(v0) + lo16(v1) + lo16(v2) + lo16(v3);
          ay += hi16(v0) + hi16(v1) + hi16(v2) + hi16(v3);
          ax += lo16(v4) + lo16(v5) + lo16(v6) + lo16(v7);
          ay += hi16(v4) + hi16(v5) + hi16(v6) + hi16(v7);
        }
        for (; j < cnt; ++j) {
          int sj = __builtin_amdgcn_readlane(idx, j);
          unsigned int v = Hin[(size_t)sj * 64 + lane];
          ax += lo16(v);
          ay += hi16(v);
        }
      }
      float d1 = (float)(e1 - e0 + 1);
      unsigned int o = (unsigned int)f2h(ax * sc0 + d1 * sh0) |
                       ((unsigned int)f2h(ay * sc1 + d1 * sh1) << 16);
      *(unsigned int*)(sTb + rl_ * 256 + ((lane * 4) ^ ((rl_ & 7) << 4))) = o;
    } else {
      *(unsigned int*)(sTb + rl_ * 256 + ((lane * 4) ^ ((rl_ & 7) << 4))) = 0u;
    }
  }
  __syncthreads();

  // ---- 8-way wave split: wr = row quadrant (16 rows), wc = col half (64) ----
  int wr = wave & 3, wc = wave >> 2;
  int lrow = lane & 15, hi = lane >> 4;
  int lk = hi * 8;
  int rl = wr * 16 + lrow;

  // GEMM1
  f16x8 af[4];
#pragma unroll
  for (int ks = 0; ks < 4; ++ks)
    af[ks] = *(const f16x8*)(sTb + rl * 256 + ((ks * 64 + hi * 16) ^ ((rl & 7) << 4)));
  f32x4 acc[4];
#pragma unroll
  for (int n = 0; n < 4; ++n) acc[n] = (f32x4){0.f, 0.f, 0.f, 0.f};
#pragma unroll
  for (int ks = 0; ks < 4; ++ks) {
    f16x8 bf[4];
#pragma unroll
    for (int n = 0; n < 4; ++n)
      bf[n] = *(const f16x8*)(WT1 + (size_t)(wc * 64 + n * 16 + lrow) * 128 + ks * 32 + lk);
#pragma unroll
    for (int n = 0; n < 4; ++n)
      acc[n] = __builtin_amdgcn_mfma_f32_16x16x32_f16(af[ks], bf[n], acc[n], 0, 0, 0);
  }
  __syncthreads();  // all waves done reading sT before overwrite

  // epilogue1: bias+ReLU -> same LDS tile (swizzled)
#pragma unroll
  for (int n = 0; n < 4; ++n) {
    int col = wc * 64 + n * 16 + lrow;
    float bia = b1[col];
#pragma unroll
    for (int r = 0; r < 4; ++r) {
      int rlw = wr * 16 + hi * 4 + r;
      float v = fmaxf(acc[n][r] + bia, 0.f);
      *(unsigned short*)(sTb + rlw * 256 + ((col * 2) ^ ((rlw & 7) << 4))) = f2h(v);
    }
  }
  __syncthreads();

  // ---- GEMM2 ----
#pragma unroll
  for (int ks = 0; ks < 4; ++ks)
    af[ks] = *(const f16x8*)(sTb + rl * 256 + ((ks * 64 + hi * 16) ^ ((rl & 7) << 4)));
#pragma unroll
  for (int n = 0; n < 4; ++n) acc[n] = (f32x4){0.f, 0.f, 0.f, 0.f};
#pragma unroll
  for (int ks = 0; ks < 4; ++ks) {
    f16x8 bf[4];
#pragma unroll
    for (int n = 0; n < 4; ++n)
      bf[n] = *(const f16x8*)(WT2 + (size_t)(wc * 64 + n * 16 + lrow) * 128 + ks * 32 + lk);
#pragma unroll
    for (int n = 0; n < 4; ++n)
      acc[n] = __builtin_amdgcn_mfma_f32_16x16x32_f16(af[ks], bf[n], acc[n], 0, 0, 0);
  }

  // epilogue2: bias+ReLU -> Hout + per-block column stats (LDS atomics only)
  int rbase = row0 + wr * 16 + hi * 4;
#pragma unroll
  for (int n = 0; n < 4; ++n) {
    int col = wc * 64 + n * 16 + lrow;
    float bia = b2[col];
    float cs = 0.f, cq = 0.f;
#pragma unroll
    for (int r = 0; r < 4; ++r) {
      int rr = rbase + r;
      float v = fmaxf(acc[n][r] + bia, 0.f);
      if (rr < M) {
        Hout[(size_t)rr * 128 + col] = f2h(v);
        cs += v;
        cq += v * v;
      }
    }
    cs += __shfl_xor(cs, 16); cs += __shfl_xor(cs, 32);
    cq += __shfl_xor(cq, 16); cq += __shfl_xor(cq, 32);
    if (hi == 0) {
      atomicAdd(&s_sum[col], cs);
      atomicAdd(&s_sq[col], cq);
    }
  }
  __syncthreads();
  if (t < 128) {
    float* p = pstat + (size_t)blockIdx.x * 256;
    p[t] = s_sum[t];
    p[t + 128] = s_sq[t];
  }
}

// reduce per-block partials -> scale/shift for the next layer (one block per column)
__global__ __launch_bounds__(256) void bn_stats_kernel(const float* __restrict__ pstat, int nb,
                                                       const float* __restrict__ gamma,
                                                       const float* __restrict__ beta,
                                                       float* __restrict__ scale,
                                                       float* __restrict__ shift, float invM) {
  int c = blockIdx.x;
  int t = threadIdx.x;
  float s = 0.f, q = 0.f;
  for (int b = t; b < nb; b += 256) {
    const float* p = pstat + (size_t)b * 256;
    s += p[c];
    q += p[c + 128];
  }
#pragma unroll
  for (int off = 1; off < 64; off <<= 1) {
    s += __shfl_xor(s, off);
    q += __shfl_xor(q, off);
  }
  __shared__ float rs[4], rq[4];
  if ((t & 63) == 0) { rs[t >> 6] = s; rq[t >> 6] = q; }
  __syncthreads();
  if (t == 0) {
    float S = rs[0] + rs[1] + rs[2] + rs[3];
    float Q = rq[0] + rq[1] + rq[2] + rq[3];
    float mean = S * invM;
    float var = fmaxf(Q * invM - mean * mean, 0.f);
    float sc = gamma[c] * rsqrtf(var + 1e-5f);
    scale[c] = sc;
    shift[c] = beta[c] - mean * sc;
  }
}

// ---- fused pool (last layer BN) + projection ----
__global__ __launch_bounds__(256) void pool_proj_kernel(const unsigned int* __restrict__ H,
                                                        const int* __restrict__ batch,
                                                        const float* __restrict__ scale,
                                                        const float* __restrict__ shift,
                                                        const float* __restrict__ Wp,
                                                        const float* __restrict__ bp,
                                                        float* __restrict__ out, int M) {
  int gid = blockIdx.x;
  int lo = 0, hi = M;
  while (lo < hi) { int mid = (lo + hi) >> 1; if (batch[mid] < gid) lo = mid + 1; else hi = mid; }
  int s = lo;
  lo = 0; hi = M;
  while (lo < hi) { int mid = (lo + hi) >> 1; if (batch[mid] < gid + 1) lo = mid + 1; else hi = mid; }
  int e = lo;
  int t = threadIdx.x;
  int cp = t & 63, rs_ = t >> 6;  // col-pair, row phase
  float ax = 0.f, ay = 0.f;
  for (int r = s + rs_; r < e; r += 4) {
    unsigned int v = H[(size_t)r * 64 + cp];
    ax += lo16(v);
    ay += hi16(v);
  }
  __shared__ float redx[256], redy[256];
  __shared__ float g[128];
  redx[t] = ax;
  redy[t] = ay;
  __syncthreads();
  if (t < 128) {
    int cpp = t >> 1;
    float sum;
    if (t & 1)
      sum = redy[cpp] + redy[64 + cpp] + redy[128 + cpp] + redy[192 + cpp];
    else
      sum = redx[cpp] + redx[64 + cpp] + redx[128 + cpp] + redx[192 + cpp];
    g[t] = sum * scale[t] + (float)(e - s) * shift[t];
  }
  __syncthreads();
  if (t < 128) {
    float a2 = bp[t];
#pragma unroll 8
    for (int k = 0; k < 128; ++k) a2 = fmaf(g[k], Wp[k * 128 + t], a2);
    out[gid * 128 + t] = fmaxf(a2, 0.f);
  }
}

extern "C" void kernel_launch(void* const* d_in, const int* in_sizes, int n_in,
                              void* d_out, int out_size, void* d_ws, size_t ws_size,
                              hipStream_t stream) {
  const float* x = (const float*)d_in[0];
  const int* ei = (const int*)d_in[1];
  const int* batch = (const int*)d_in[2];
  const float* W1 = (const float*)d_in[3];
  const float* b1 = (const float*)d_in[4];
  const float* W2 = (const float*)d_in[5];
  const float* b2 = (const float*)d_in[6];
  const float* gamma = (const float*)d_in[7];
  const float* beta = (const float*)d_in[8];
  const float* Wp = (const float*)d_in[9];
  const float* bp = (const float*)d_in[10];
  float* out = (float*)d_out;

  int M = in_sizes[0] / 128;
  int E = in_sizes[1] / 2;
  int L = in_sizes[3] / (128 * 128);
  int G = out_size / 128;
  const int* srcp = ei;
  const int* dstp = ei + E;

  char* w = (char*)d_ws;
  auto alloc = [&](size_t bytes) {
    char* p = w;
    w += (bytes + 255) & ~(size_t)255;
    return p;
  };
  int nblk = (M + 63) / 64;
  unsigned int* bufA = (unsigned int*)alloc((size_t)M * 64 * 4);
  unsigned int* bufB = (unsigned int*)alloc((size_t)M * 64 * 4);
  unsigned short* WT = (unsigned short*)alloc((size_t)L * 2 * 16384 * 2);
  int* counts = (int*)alloc((size_t)M * 4);
  int* incl = (int*)alloc((size_t)M * 4);
  int* bsums = (int*)alloc(128 * 4);
  int* offsets = (int*)alloc((size_t)(M + 1) * 4);
  int* cursor = (int*)alloc((size_t)M * 4);
  int* srcs = (int*)alloc((size_t)E * 4);
  float* pstat = (float*)alloc((size_t)nblk * 256 * 4);
  float* stats = (float*)alloc(2 * 128 * 4);
  float* scale = stats;
  float* shift = stats + 128;

  int nb = (M + 511) / 512;

  prep_kernel<<<2048, 256, 0, stream>>>(x, bufA, counts, scale, shift, M);
  hist_kernel<<<(E + 255) / 256, 256, 0, stream>>>(dstp, counts, E);
  scan1_kernel<<<nb, 512, 0, stream>>>(counts, incl, bsums, M);
  scan2_kernel<<<1, 128, 0, stream>>>(bsums, nb);
  scan3_kernel<<<(M + 255) / 256, 256, 0, stream>>>(counts, incl, bsums, offsets, cursor, M);
  fill_kernel<<<(E + 255) / 256, 256, 0, stream>>>(srcp, dstp, cursor, srcs, E);
  prep_w_kernel<<<(L * 2 * 16384 + 255) / 256, 256, 0, stream>>>(W1, W2, WT, L * 2 * 16384);

  float invM = 1.0f / (float)M;
  unsigned int* cur = bufA;
  unsigned int* nxt = bufB;
  for (int l = 0; l < L; ++l) {
    layer_kernel<<<nblk, 512, 0, stream>>>(
        cur, offsets, srcs, scale, shift, WT + (size_t)(2 * l) * 16384, b1 + l * 128,
        WT + (size_t)(2 * l + 1) * 16384, b2 + l * 128, (unsigned short*)nxt, pstat, M);
    bn_stats_kernel<<<128, 256, 0, stream>>>(pstat, nblk, gamma + l * 128, beta + l * 128,
                                             scale, shift, invM);
    unsigned int* tmp = cur; cur = nxt; nxt = tmp;
  }

  pool_proj_kernel<<<G, 256, 0, stream>>>(cur, batch, scale, shift, Wp, bp, out, M);
}